// Round 5
// baseline (696.787 us; speedup 1.0000x reference)
//
#include <hip/hip_runtime.h>
#include <hip/hip_fp16.h>
#include <math.h>

#define EPS 1e-8f
#define AS1 __attribute__((address_space(1)))
#define AS3 __attribute__((address_space(3)))

typedef _Float16 f16x8 __attribute__((ext_vector_type(8)));
typedef float f32x4 __attribute__((ext_vector_type(4)));

// ---------------- generic [R][C] -> [C][R] transpose (64x64 LDS tiles) ----------------
__global__ __launch_bounds__(256) void transpose_k(const float* __restrict__ in,
                                                   float* __restrict__ out, int R, int C) {
    __shared__ float tile[64][65];
    int tx = threadIdx.x & 63, ty = threadIdx.x >> 6;
    int c0 = blockIdx.x * 64, r0 = blockIdx.y * 64;
#pragma unroll
    for (int i = 0; i < 16; ++i) {
        int r = r0 + ty + i * 4, c = c0 + tx;
        if (r < R && c < C) tile[ty + i * 4][tx] = in[(long)r * C + c];
    }
    __syncthreads();
#pragma unroll
    for (int i = 0; i < 16; ++i) {
        int r = c0 + ty + i * 4, c = r0 + tx;
        if (r < C && c < R) out[(long)r * R + c] = tile[tx][ty + i * 4];
    }
}

// -------- weight prep: prim_w [co][ci][81] f32 -> w2 [co][tap][ci] fp16 ----------------
__global__ __launch_bounds__(256) void wprep_k(const float* __restrict__ prim_w,
                                               __half* __restrict__ w2) {
    __shared__ float pl[128 * 81];
    int t = threadIdx.x, co = blockIdx.x, cih = blockIdx.y;
    for (int i = t; i < 10368; i += 256) pl[i] = prim_w[co * 20736 + cih * 10368 + i];
    __syncthreads();
    for (int o = t; o < 10368; o += 256) {  // o = tap*128 + cil
        int tap = o >> 7, cil = o & 127;
        w2[(long)co * 20736 + tap * 256 + cih * 128 + cil] = __float2half(pl[cil * 81 + tap]);
    }
}

// ---------------- conv1 9x9 stride1 + bias + relu -> hh [b][400 pix][256 ci] fp16 -------
// grid (256 images, 4 = chalf*2 + pixhalf)
__global__ __launch_bounds__(256) void conv1_k(const float* __restrict__ x,
                                               const float* __restrict__ wt1,  // [81][256]
                                               const float* __restrict__ bias,
                                               __half* __restrict__ hh) {
    __shared__ float img[784];
    __shared__ float wl2[81 * 128];
    int t = threadIdx.x, b = blockIdx.x;
    int chalf = blockIdx.y >> 1, ph = blockIdx.y & 1;
    for (int i = t; i < 784; i += 256) img[i] = x[b * 784 + i];
    for (int i = t; i < 81 * 128; i += 256) {
        int tap = i >> 7, j = i & 127;
        wl2[i] = wt1[tap * 256 + chalf * 128 + j];
    }
    __syncthreads();
    int lane = t & 63, grp = t >> 6;
    int col = lane * 2;
    float2 cb = *(const float2*)&bias[chalf * 128 + col];
    int ow0 = ph * 10;
    for (int oh = grp * 5; oh < grp * 5 + 5; ++oh) {
        float acc0[10], acc1[10];
#pragma unroll
        for (int p = 0; p < 10; ++p) { acc0[p] = 0.f; acc1[p] = 0.f; }
        for (int kh = 0; kh < 9; ++kh) {
            for (int kw = 0; kw < 9; ++kw) {
                float2 w2v = *(const float2*)&wl2[(kh * 9 + kw) * 128 + col];
                const float* irow = &img[(oh + kh) * 28 + ow0 + kw];
#pragma unroll
                for (int p = 0; p < 10; ++p) {
                    float iv = irow[p];
                    acc0[p] += iv * w2v.x;
                    acc1[p] += iv * w2v.y;
                }
            }
        }
#pragma unroll
        for (int p = 0; p < 10; ++p) {
            int pix = oh * 20 + ow0 + p;
            __half2 hv;
            hv.x = __float2half(fmaxf(acc0[p] + cb.x, 0.f));
            hv.y = __float2half(fmaxf(acc1[p] + cb.y, 0.f));
            *(__half2*)&hh[((long)b * 400 + pix) * 256 + chalf * 128 + col] = hv;
        }
    }
}

// ---------------- primary-caps implicit GEMM v3 ----------------------------------------
// ci-based K-split: slice ks owns ci [ks*64, ks*64+64); 81 tap-steps of BK=64.
// Block: 128 m x 128 co, 4 waves, wave tile 64x64 (4 mf x 4 nf, acc 64 VGPR).
__global__ __launch_bounds__(256) void primgemm_k(const __half* __restrict__ hh,
                                                  const __half* __restrict__ w2,
                                                  float* __restrict__ Cpart) {
    __shared__ __align__(16) char lds[2][32768];  // [buf][ W 16K | A 16K ]
    const int t = threadIdx.x;
    const int lane = t & 63, w = t >> 6;
    const int l15 = lane & 15, kl = lane >> 4;
    const int sw = l15 & 7;

    const int bx = blockIdx.x;
    const int mt = bx >> 3, nb = (bx >> 2) & 1, ks = bx & 3;
    const int mr = w >> 1, nc = w & 1;

    long wsrc[4], asrc[4];
    int dstW[4];
#pragma unroll
    for (int q = 0; q < 4; ++q) {
        int row = q * 32 + w * 8 + (lane >> 3);
        int lc = (lane & 7) ^ (row & 7);
        dstW[q] = q * 4096 + w * 1024;
        wsrc[q] = (long)(nb * 128 + row) * 20736 + ks * 64 + lc * 8;
        int m = mt * 128 + row;
        int bi = m / 36, pos = m - bi * 36;
        int oy = pos / 6, ox = pos - oy * 6;
        asrc[q] = ((long)bi * 400 + oy * 40 + ox * 2) * 256 + ks * 64 + lc * 8;
    }

    f32x4 acc[4][4];
#pragma unroll
    for (int i = 0; i < 4; ++i)
#pragma unroll
        for (int j = 0; j < 4; ++j) acc[i][j] = (f32x4){0.f, 0.f, 0.f, 0.f};

    auto stage = [&](int bufi, int tap) {
        int kh = tap / 9, kw = tap - kh * 9;
        int woff = tap * 256;
        int aoff = (kh * 20 + kw) * 256;
#pragma unroll
        for (int q = 0; q < 4; ++q)
            __builtin_amdgcn_global_load_lds((const AS1 void*)(w2 + wsrc[q] + woff),
                                             (AS3 void*)(&lds[bufi][dstW[q]]), 16, 0, 0);
#pragma unroll
        for (int q = 0; q < 4; ++q)
            __builtin_amdgcn_global_load_lds((const AS1 void*)(hh + asrc[q] + aoff),
                                             (AS3 void*)(&lds[bufi][16384 + dstW[q]]), 16, 0, 0);
    };

    int wrowb[4], arowb[4], rdoff[2];
#pragma unroll
    for (int f = 0; f < 4; ++f) {
        wrowb[f] = (nc * 64 + f * 16 + l15) * 128;
        arowb[f] = 16384 + (mr * 64 + f * 16 + l15) * 128;
    }
#pragma unroll
    for (int kc = 0; kc < 2; ++kc) rdoff[kc] = ((kc * 4 + kl) ^ sw) << 4;

    stage(0, 0);
    __syncthreads();
    int buf = 0;
    for (int s = 0; s < 81; ++s) {
        if (s < 80) stage(buf ^ 1, s + 1);
        const char* B = lds[buf];
#pragma unroll
        for (int kc = 0; kc < 2; ++kc) {
            f16x8 wf[4], af[4];
#pragma unroll
            for (int nf = 0; nf < 4; ++nf) wf[nf] = *(const f16x8*)(B + wrowb[nf] + rdoff[kc]);
#pragma unroll
            for (int mf = 0; mf < 4; ++mf) af[mf] = *(const f16x8*)(B + arowb[mf] + rdoff[kc]);
#pragma unroll
            for (int mf = 0; mf < 4; ++mf)
#pragma unroll
                for (int nf = 0; nf < 4; ++nf)
                    acc[mf][nf] = __builtin_amdgcn_mfma_f32_16x16x32_f16(wf[nf], af[mf],
                                                                         acc[mf][nf], 0, 0, 0);
        }
        __syncthreads();
        buf ^= 1;
    }

    float* Cp = Cpart + (long)ks * 2359296;
#pragma unroll
    for (int mf = 0; mf < 4; ++mf)
#pragma unroll
        for (int nf = 0; nf < 4; ++nf) {
            int m = mt * 128 + mr * 64 + mf * 16 + l15;
            int co = nb * 128 + nc * 64 + nf * 16 + kl * 4;
            *(f32x4*)(Cp + (long)m * 256 + co) = acc[mf][nf];
        }
}

// -------------- sum 4 K-partials + bias + capsule regroup + squash -> u ----------------
__global__ __launch_bounds__(256) void squashp_k(const float* __restrict__ Cpart,
                                                 const float* __restrict__ bias,
                                                 float* __restrict__ u) {
    __shared__ float sm[9216];  // [pos][co]
    __shared__ float bs[256];
    int t = threadIdx.x, b = blockIdx.x;
    bs[t] = bias[t];
    for (int i = t; i < 9216; i += 256) {
        float s = 0.f;
#pragma unroll
        for (int ks = 0; ks < 4; ++ks) s += Cpart[(long)ks * 2359296 + (long)b * 9216 + i];
        sm[i] = s;
    }
    __syncthreads();
    for (int cap = t; cap < 1152; cap += 256) {
        float xs[8], sn = 0.f;
#pragma unroll
        for (int d = 0; d < 8; ++d) {
            int f = cap * 8 + d;
            int co = f / 36, pos = f - co * 36;
            float vv = sm[pos * 256 + co] + bs[co];
            xs[d] = vv;
            sn += vv * vv;
        }
        float sc = sn / ((sn + 1.f) * (sqrtf(sn) + EPS));
#pragma unroll
        for (int d = 0; d < 8; ++d) u[(long)b * 9216 + cap * 8 + d] = xs[d] * sc;
    }
}

// -------------- u_hat + 3-iter dynamic routing v2: u_hat in REGISTERS ------------------
// Block = (c,b), 256 threads; thread t owns n in {t, t+256, ..} (5 slots, tail masked).
// uh[5][16] statically indexed (rule #20). Block reductions: wave shfl_xor + 4x18 LDS.
__global__ __launch_bounds__(256) void route_k(const float* __restrict__ u,
                                               const float* __restrict__ W,  // [10][1152][8][16]
                                               float* __restrict__ v) {
    __shared__ float red[4][18];
    int t = threadIdx.x;
    int c = blockIdx.x >> 8, b = blockIdx.x & 255;
    int lane = t & 63, w = t >> 6;
    const float* Wc = W + c * 147456;
    const float* ub = u + b * 9216;
    const float valid4 = (t < 128) ? 1.f : 0.f;

    // ---- phase 1: u_hat rows for owned n's, fully in registers ----
    float uh[5][16];
#pragma unroll
    for (int i = 0; i < 5; ++i) {
        int n = (i == 4) ? ((t < 128) ? 1024 + t : 0) : (t + 256 * i);
        float4 ua = *(const float4*)(ub + n * 8);
        float4 ubv = *(const float4*)(ub + n * 8 + 4);
        float ud[8] = {ua.x, ua.y, ua.z, ua.w, ubv.x, ubv.y, ubv.z, ubv.w};
#pragma unroll
        for (int e = 0; e < 16; ++e) uh[i][e] = 0.f;
#pragma unroll
        for (int d = 0; d < 8; ++d) {
            const float* wr = Wc + n * 128 + d * 16;
#pragma unroll
            for (int eq = 0; eq < 4; ++eq) {
                float4 wq = *(const float4*)(wr + eq * 4);
                uh[i][eq * 4 + 0] += ud[d] * wq.x;
                uh[i][eq * 4 + 1] += ud[d] * wq.y;
                uh[i][eq * 4 + 2] += ud[d] * wq.z;
                uh[i][eq * 4 + 3] += ud[d] * wq.w;
            }
        }
    }

    // ---- phase 2: 3 routing iterations ----
    float vsum[16], sv[16];
#pragma unroll
    for (int e = 0; e < 16; ++e) vsum[e] = 0.f;

    for (int iter = 0; iter < 3; ++iter) {
        float li[5];
        float pmax = -1e30f;
#pragma unroll
        for (int i = 0; i < 5; ++i) {
            float s = 0.f;
#pragma unroll
            for (int e = 0; e < 16; ++e) s += uh[i][e] * vsum[e];
            li[i] = s;
            float sm = (i == 4 && valid4 == 0.f) ? -1e30f : s;
            pmax = fmaxf(pmax, sm);
        }
#pragma unroll
        for (int m = 1; m < 64; m <<= 1) pmax = fmaxf(pmax, __shfl_xor(pmax, m, 64));
        if (lane == 0) red[w][17] = pmax;
        __syncthreads();
        float M = fmaxf(fmaxf(red[0][17], red[1][17]), fmaxf(red[2][17], red[3][17]));

        float pe = 0.f, se[16];
#pragma unroll
        for (int e = 0; e < 16; ++e) se[e] = 0.f;
#pragma unroll
        for (int i = 0; i < 5; ++i) {
            float E = __expf(li[i] - M);
            if (i == 4) E *= valid4;
            pe += E;
#pragma unroll
            for (int e = 0; e < 16; ++e) se[e] += E * uh[i][e];
        }
#pragma unroll
        for (int m = 1; m < 64; m <<= 1) {
            pe += __shfl_xor(pe, m, 64);
#pragma unroll
            for (int e = 0; e < 16; ++e) se[e] += __shfl_xor(se[e], m, 64);
        }
        if (lane == 0) {
            red[w][16] = pe;
#pragma unroll
            for (int e = 0; e < 16; ++e) red[w][e] = se[e];
        }
        __syncthreads();
        float peT = red[0][16] + red[1][16] + red[2][16] + red[3][16];
        float rp = 1.f / peT;
        float nrm = 0.f;
#pragma unroll
        for (int e = 0; e < 16; ++e) {
            sv[e] = (red[0][e] + red[1][e] + red[2][e] + red[3][e]) * rp;
            nrm += sv[e] * sv[e];
        }
        float sc = nrm / ((nrm + 1.f) * (sqrtf(nrm) + EPS));
#pragma unroll
        for (int e = 0; e < 16; ++e) {
            sv[e] *= sc;
            vsum[e] += sv[e];
        }
    }
    if (t == 0) {
#pragma unroll
        for (int e = 0; e < 16; ++e) v[(b * 10 + c) * 16 + e] = sv[e];
    }
}

// -------------- logits = softmax over c of ||v|| ---------------------------------------
__global__ __launch_bounds__(256) void logits_k(const float* __restrict__ v,
                                                float* __restrict__ out) {
    int b = threadIdx.x;
    float nr[10];
#pragma unroll
    for (int c = 0; c < 10; ++c) {
        float s2 = 0.f;
#pragma unroll
        for (int e = 0; e < 16; ++e) {
            float xv = v[(b * 10 + c) * 16 + e];
            s2 += xv * xv;
        }
        nr[c] = sqrtf(s2);
    }
    float mx = nr[0];
#pragma unroll
    for (int c = 1; c < 10; ++c) mx = fmaxf(mx, nr[c]);
    float ex[10], sm = 0.f;
#pragma unroll
    for (int c = 0; c < 10; ++c) {
        ex[c] = __expf(nr[c] - mx);
        sm += ex[c];
    }
#pragma unroll
    for (int c = 0; c < 10; ++c) out[b * 10 + c] = ex[c] / sm;
}

// -------------- fc1: picks the 16 columns selected by y ------------------------------
__global__ __launch_bounds__(256) void fc1_k(const float* __restrict__ v,
                                             const int* __restrict__ y,
                                             const float* __restrict__ w1,
                                             const float* __restrict__ b1,
                                             float* __restrict__ h1) {
    int b = blockIdx.x, t = threadIdx.x;
    __shared__ float vs[16];
    int cls = y[b];
    if (t < 16) vs[t] = v[(b * 10 + cls) * 16 + t];
    __syncthreads();
    for (int j = t; j < 512; j += 256) {
        float a = b1[j];
#pragma unroll
        for (int d = 0; d < 16; ++d) a += vs[d] * w1[(cls * 16 + d) * 512 + j];
        h1[b * 512 + j] = fmaxf(a, 0.f);
    }
}

// -------------- generic fc: C[256,N] = (relu?)(A[256,K] @ W[K,N] + bias) ---------------
__global__ __launch_bounds__(256) void fc_k(const float* __restrict__ A,
                                            const float* __restrict__ Wt,
                                            const float* __restrict__ bias,
                                            float* __restrict__ C,
                                            int K, int N, int relu) {
    __shared__ float al[8 * 1024];
    int t = threadIdx.x;
    int j = blockIdx.x * 256 + t;
    int r0 = blockIdx.y * 8;
    for (int idx = t; idx < 8 * K; idx += 256) {
        int r = idx / K, kk = idx - r * K;
        al[r * K + kk] = A[(r0 + r) * K + kk];
    }
    __syncthreads();
    if (j < N) {
        float bj = bias[j];
        float acc[8];
#pragma unroll
        for (int i = 0; i < 8; ++i) acc[i] = bj;
        for (int k = 0; k < K; ++k) {
            float w = Wt[(long)k * N + j];
#pragma unroll
            for (int i = 0; i < 8; ++i) acc[i] += al[i * K + k] * w;
        }
#pragma unroll
        for (int i = 0; i < 8; ++i) {
            float o = acc[i];
            if (relu) o = fmaxf(o, 0.f);
            C[(r0 + i) * N + j] = o;
        }
    }
}

extern "C" void kernel_launch(void* const* d_in, const int* in_sizes, int n_in,
                              void* d_out, int out_size, void* d_ws, size_t ws_size,
                              hipStream_t stream) {
    (void)in_sizes; (void)n_in; (void)out_size; (void)ws_size;
    const float* x       = (const float*)d_in[0];
    const int*   y       = (const int*)d_in[1];
    const float* conv1_w = (const float*)d_in[2];
    const float* conv1_b = (const float*)d_in[3];
    const float* prim_w  = (const float*)d_in[4];
    const float* prim_b  = (const float*)d_in[5];
    const float* route_W = (const float*)d_in[6];
    const float* dec_w1  = (const float*)d_in[7];
    const float* dec_b1  = (const float*)d_in[8];
    const float* dec_w2  = (const float*)d_in[9];
    const float* dec_b2  = (const float*)d_in[10];
    const float* dec_w3  = (const float*)d_in[11];
    const float* dec_b3  = (const float*)d_in[12];
    float* out = (float*)d_out;

    float* ws  = (float*)d_ws;
    float* Cp  = ws;                  // 4 * 2359296 f32 (ci-split partials)
    float* u   = Cp + 9437184;        // 2359296
    float* wt1 = u + 2359296;         // 20736
    float* v   = wt1 + 20736;         // 40960
    float* h1  = v + 40960;           // 131072
    float* h2  = h1 + 131072;         // 262144
    __half* hh = (__half*)(h2 + 262144);   // 26214400 halfs
    __half* w2 = hh + 26214400;            // 5308416 halfs

    hipLaunchKernelGGL(transpose_k, dim3(2, 4), dim3(256), 0, stream, conv1_w, wt1, 256, 81);
    hipLaunchKernelGGL(wprep_k, dim3(256, 2), dim3(256), 0, stream, prim_w, w2);
    hipLaunchKernelGGL(conv1_k, dim3(256, 4), dim3(256), 0, stream, x, wt1, conv1_b, hh);
    hipLaunchKernelGGL(primgemm_k, dim3(576), dim3(256), 0, stream, hh, w2, Cp);
    hipLaunchKernelGGL(squashp_k, dim3(256), dim3(256), 0, stream, Cp, prim_b, u);
    hipLaunchKernelGGL(route_k, dim3(2560), dim3(256), 0, stream, u, route_W, v);
    hipLaunchKernelGGL(logits_k, dim3(1), dim3(256), 0, stream, v, out);
    hipLaunchKernelGGL(fc1_k, dim3(256), dim3(256), 0, stream, v, y, dec_w1, dec_b1, h1);
    hipLaunchKernelGGL(fc_k, dim3(4, 32), dim3(256), 0, stream, h1, dec_w2, dec_b2, h2, 512, 1024, 1);
    hipLaunchKernelGGL(fc_k, dim3(4, 32), dim3(256), 0, stream, h2, dec_w3, dec_b3, out + 2560, 1024, 784, 0);
}

// Round 6
// 581.337 us; speedup vs baseline: 1.1986x; 1.1986x over previous
//
#include <hip/hip_runtime.h>
#include <hip/hip_fp16.h>
#include <math.h>

#define EPS 1e-8f
#define AS1 __attribute__((address_space(1)))
#define AS3 __attribute__((address_space(3)))

typedef _Float16 f16x8 __attribute__((ext_vector_type(8)));
typedef float f32x4 __attribute__((ext_vector_type(4)));

// ---------------- generic [R][C] -> [C][R] transpose (64x64 LDS tiles) ----------------
__global__ __launch_bounds__(256) void transpose_k(const float* __restrict__ in,
                                                   float* __restrict__ out, int R, int C) {
    __shared__ float tile[64][65];
    int tx = threadIdx.x & 63, ty = threadIdx.x >> 6;
    int c0 = blockIdx.x * 64, r0 = blockIdx.y * 64;
#pragma unroll
    for (int i = 0; i < 16; ++i) {
        int r = r0 + ty + i * 4, c = c0 + tx;
        if (r < R && c < C) tile[ty + i * 4][tx] = in[(long)r * C + c];
    }
    __syncthreads();
#pragma unroll
    for (int i = 0; i < 16; ++i) {
        int r = c0 + ty + i * 4, c = r0 + tx;
        if (r < C && c < R) out[(long)r * R + c] = tile[tx][ty + i * 4];
    }
}

// -------- weight prep: prim_w [co][ci][81] f32 -> w2 [co][tap][ci] fp16 ----------------
__global__ __launch_bounds__(256) void wprep_k(const float* __restrict__ prim_w,
                                               __half* __restrict__ w2) {
    __shared__ float pl[128 * 81];
    int t = threadIdx.x, co = blockIdx.x, cih = blockIdx.y;
    for (int i = t; i < 10368; i += 256) pl[i] = prim_w[co * 20736 + cih * 10368 + i];
    __syncthreads();
    for (int o = t; o < 10368; o += 256) {  // o = tap*128 + cil
        int tap = o >> 7, cil = o & 127;
        w2[(long)co * 20736 + tap * 256 + cih * 128 + cil] = __float2half(pl[cil * 81 + tap]);
    }
}

// ---------------- conv1 9x9 stride1 + bias + relu -> hh [b][400 pix][256 ci] fp16 -------
// grid (256 images, 4 = chalf*2 + pixhalf). Sliding-window register rows per kh.
__global__ __launch_bounds__(256) void conv1_k(const float* __restrict__ x,
                                               const float* __restrict__ wt1,  // [81][256]
                                               const float* __restrict__ bias,
                                               __half* __restrict__ hh) {
    __shared__ float img[784];
    __shared__ float wl2[81 * 128];
    int t = threadIdx.x, b = blockIdx.x;
    int chalf = blockIdx.y >> 1, ph = blockIdx.y & 1;
    for (int i = t; i < 784; i += 256) img[i] = x[b * 784 + i];
    for (int i = t; i < 81 * 128; i += 256) {
        int tap = i >> 7, j = i & 127;
        wl2[i] = wt1[tap * 256 + chalf * 128 + j];
    }
    __syncthreads();
    int lane = t & 63, grp = t >> 6;
    int col = lane * 2;
    float2 cb = *(const float2*)&bias[chalf * 128 + col];
    int ow0 = ph * 10;
    for (int oh = grp * 5; oh < grp * 5 + 5; ++oh) {
        float acc0[10], acc1[10];
#pragma unroll
        for (int p = 0; p < 10; ++p) { acc0[p] = 0.f; acc1[p] = 0.f; }
#pragma unroll
        for (int kh = 0; kh < 9; ++kh) {
            float r[19];
            const float* irow = &img[(oh + kh) * 28 + ow0];
#pragma unroll
            for (int q = 0; q < 19; ++q) r[q] = irow[q];
#pragma unroll
            for (int kw = 0; kw < 9; ++kw) {
                float2 wv = *(const float2*)&wl2[(kh * 9 + kw) * 128 + col];
#pragma unroll
                for (int p = 0; p < 10; ++p) {
                    acc0[p] += r[kw + p] * wv.x;
                    acc1[p] += r[kw + p] * wv.y;
                }
            }
        }
#pragma unroll
        for (int p = 0; p < 10; ++p) {
            int pix = oh * 20 + ow0 + p;
            __half2 hv;
            hv.x = __float2half(fmaxf(acc0[p] + cb.x, 0.f));
            hv.y = __float2half(fmaxf(acc1[p] + cb.y, 0.f));
            *(__half2*)&hh[((long)b * 400 + pix) * 256 + chalf * 128 + col] = hv;
        }
    }
}

// ---------------- primary-caps implicit GEMM v3 ----------------------------------------
__global__ __launch_bounds__(256) void primgemm_k(const __half* __restrict__ hh,
                                                  const __half* __restrict__ w2,
                                                  float* __restrict__ Cpart) {
    __shared__ __align__(16) char lds[2][32768];  // [buf][ W 16K | A 16K ]
    const int t = threadIdx.x;
    const int lane = t & 63, w = t >> 6;
    const int l15 = lane & 15, kl = lane >> 4;
    const int sw = l15 & 7;

    const int bx = blockIdx.x;
    const int mt = bx >> 3, nb = (bx >> 2) & 1, ks = bx & 3;
    const int mr = w >> 1, nc = w & 1;

    long wsrc[4], asrc[4];
    int dstW[4];
#pragma unroll
    for (int q = 0; q < 4; ++q) {
        int row = q * 32 + w * 8 + (lane >> 3);
        int lc = (lane & 7) ^ (row & 7);
        dstW[q] = q * 4096 + w * 1024;
        wsrc[q] = (long)(nb * 128 + row) * 20736 + ks * 64 + lc * 8;
        int m = mt * 128 + row;
        int bi = m / 36, pos = m - bi * 36;
        int oy = pos / 6, ox = pos - oy * 6;
        asrc[q] = ((long)bi * 400 + oy * 40 + ox * 2) * 256 + ks * 64 + lc * 8;
    }

    f32x4 acc[4][4];
#pragma unroll
    for (int i = 0; i < 4; ++i)
#pragma unroll
        for (int j = 0; j < 4; ++j) acc[i][j] = (f32x4){0.f, 0.f, 0.f, 0.f};

    auto stage = [&](int bufi, int tap) {
        int kh = tap / 9, kw = tap - kh * 9;
        int woff = tap * 256;
        int aoff = (kh * 20 + kw) * 256;
#pragma unroll
        for (int q = 0; q < 4; ++q)
            __builtin_amdgcn_global_load_lds((const AS1 void*)(w2 + wsrc[q] + woff),
                                             (AS3 void*)(&lds[bufi][dstW[q]]), 16, 0, 0);
#pragma unroll
        for (int q = 0; q < 4; ++q)
            __builtin_amdgcn_global_load_lds((const AS1 void*)(hh + asrc[q] + aoff),
                                             (AS3 void*)(&lds[bufi][16384 + dstW[q]]), 16, 0, 0);
    };

    int wrowb[4], arowb[4], rdoff[2];
#pragma unroll
    for (int f = 0; f < 4; ++f) {
        wrowb[f] = (nc * 64 + f * 16 + l15) * 128;
        arowb[f] = 16384 + (mr * 64 + f * 16 + l15) * 128;
    }
#pragma unroll
    for (int kc = 0; kc < 2; ++kc) rdoff[kc] = ((kc * 4 + kl) ^ sw) << 4;

    stage(0, 0);
    __syncthreads();
    int buf = 0;
    for (int s = 0; s < 81; ++s) {
        if (s < 80) stage(buf ^ 1, s + 1);
        const char* B = lds[buf];
#pragma unroll
        for (int kc = 0; kc < 2; ++kc) {
            f16x8 wf[4], af[4];
#pragma unroll
            for (int nf = 0; nf < 4; ++nf) wf[nf] = *(const f16x8*)(B + wrowb[nf] + rdoff[kc]);
#pragma unroll
            for (int mf = 0; mf < 4; ++mf) af[mf] = *(const f16x8*)(B + arowb[mf] + rdoff[kc]);
#pragma unroll
            for (int mf = 0; mf < 4; ++mf)
#pragma unroll
                for (int nf = 0; nf < 4; ++nf)
                    acc[mf][nf] = __builtin_amdgcn_mfma_f32_16x16x32_f16(wf[nf], af[mf],
                                                                         acc[mf][nf], 0, 0, 0);
        }
        __syncthreads();
        buf ^= 1;
    }

    float* Cp = Cpart + (long)ks * 2359296;
#pragma unroll
    for (int mf = 0; mf < 4; ++mf)
#pragma unroll
        for (int nf = 0; nf < 4; ++nf) {
            int m = mt * 128 + mr * 64 + mf * 16 + l15;
            int co = nb * 128 + nc * 64 + nf * 16 + kl * 4;
            *(f32x4*)(Cp + (long)m * 256 + co) = acc[mf][nf];
        }
}

// -------------- sum 4 K-partials + bias + capsule regroup + squash -> u ----------------
__global__ __launch_bounds__(256) void squashp_k(const float* __restrict__ Cpart,
                                                 const float* __restrict__ bias,
                                                 float* __restrict__ u) {
    __shared__ float sm[9216];  // [pos][co]
    __shared__ float bs[256];
    int t = threadIdx.x, b = blockIdx.x;
    bs[t] = bias[t];
    for (int i = t; i < 9216; i += 256) {
        float s = 0.f;
#pragma unroll
        for (int ks = 0; ks < 4; ++ks) s += Cpart[(long)ks * 2359296 + (long)b * 9216 + i];
        sm[i] = s;
    }
    __syncthreads();
    for (int cap = t; cap < 1152; cap += 256) {
        float xs[8], sn = 0.f;
#pragma unroll
        for (int d = 0; d < 8; ++d) {
            int f = cap * 8 + d;
            int co = f / 36, pos = f - co * 36;
            float vv = sm[pos * 256 + co] + bs[co];
            xs[d] = vv;
            sn += vv * vv;
        }
        float sc = sn / ((sn + 1.f) * (sqrtf(sn) + EPS));
#pragma unroll
        for (int d = 0; d < 8; ++d) u[(long)b * 9216 + cap * 8 + d] = xs[d] * sc;
    }
}

// -------------- u_hat precompute: uh[c][b][n][e] fp16 ----------------------------------
// block = (c, 32-n chunk); W slice staged once in LDS (padded), loop over all 256 b.
// Kills the 256x per-b re-read of route_W that made routing latency/L2-bound.
__global__ __launch_bounds__(256) void uhat_k(const float* __restrict__ u,
                                              const float* __restrict__ W,  // [10][1152][8][16]
                                              __half* __restrict__ uh) {
    __shared__ float wl[32 * 132];  // [n_local][128+4 pad] -> conflict-free 8-group bcast
    int t = threadIdx.x;
    int c = blockIdx.x / 36, ng = blockIdx.x - c * 36;
    const float* Wc = W + (long)c * 147456 + ng * 4096;
    for (int i = t; i < 4096; i += 256) {
        int row = i >> 7, k = i & 127;
        wl[row * 132 + k] = Wc[i];
    }
    __syncthreads();
    int nl = t >> 3, bl = t & 7;
    int n = ng * 32 + nl;
    const float* wr = &wl[nl * 132];
    for (int bq = 0; bq < 32; ++bq) {
        int b = bq * 8 + bl;
        const float* ub = u + (long)b * 9216 + n * 8;
        float4 ua = *(const float4*)ub, uv = *(const float4*)(ub + 4);
        float ud[8] = {ua.x, ua.y, ua.z, ua.w, uv.x, uv.y, uv.z, uv.w};
        float acc[16];
#pragma unroll
        for (int e = 0; e < 16; ++e) acc[e] = 0.f;
#pragma unroll
        for (int d = 0; d < 8; ++d) {
            const float* wd = wr + d * 16;
#pragma unroll
            for (int eq = 0; eq < 4; ++eq) {
                float4 wq = *(const float4*)(wd + eq * 4);
                acc[eq * 4 + 0] += ud[d] * wq.x;
                acc[eq * 4 + 1] += ud[d] * wq.y;
                acc[eq * 4 + 2] += ud[d] * wq.z;
                acc[eq * 4 + 3] += ud[d] * wq.w;
            }
        }
        f16x8 o0, o1;
#pragma unroll
        for (int e = 0; e < 8; ++e) {
            o0[e] = (_Float16)acc[e];
            o1[e] = (_Float16)acc[8 + e];
        }
        __half* dst = uh + ((long)(c * 256 + b)) * 18432 + n * 16;
        *(f16x8*)dst = o0;
        *(f16x8*)(dst + 8) = o1;
    }
}

// -------------- 3-iter dynamic routing from precomputed fp16 u_hat ---------------------
// Block = (c,b); thread t owns n in {t, t+256, ..} (5 slots, tail masked); uh fp16 regs.
__global__ __launch_bounds__(256) void route2_k(const __half* __restrict__ uh,
                                                float* __restrict__ v) {
    __shared__ float red[4][18];
    int t = threadIdx.x;
    int c = blockIdx.x >> 8, b = blockIdx.x & 255;
    int lane = t & 63, w = t >> 6;
    const float valid4 = (t < 128) ? 1.f : 0.f;
    const __half* ub = uh + ((long)(c * 256 + b)) * 18432;

    f16x8 uhh[5][2];
#pragma unroll
    for (int i = 0; i < 5; ++i) {
        int n = (i == 4) ? ((t < 128) ? 1024 + t : 0) : (t + 256 * i);
        const __half* p = ub + n * 16;
        uhh[i][0] = *(const f16x8*)p;
        uhh[i][1] = *(const f16x8*)(p + 8);
    }

    float vsum[16], sv[16];
#pragma unroll
    for (int e = 0; e < 16; ++e) vsum[e] = 0.f;

    for (int iter = 0; iter < 3; ++iter) {
        float li[5];
        float pmax = -1e30f;
#pragma unroll
        for (int i = 0; i < 5; ++i) {
            float s = 0.f;
#pragma unroll
            for (int e = 0; e < 16; ++e) s += (float)uhh[i][e >> 3][e & 7] * vsum[e];
            li[i] = s;
            float sm = (i == 4 && valid4 == 0.f) ? -1e30f : s;
            pmax = fmaxf(pmax, sm);
        }
#pragma unroll
        for (int m = 1; m < 64; m <<= 1) pmax = fmaxf(pmax, __shfl_xor(pmax, m, 64));
        if (lane == 0) red[w][17] = pmax;
        __syncthreads();
        float M = fmaxf(fmaxf(red[0][17], red[1][17]), fmaxf(red[2][17], red[3][17]));

        float pe = 0.f, se[16];
#pragma unroll
        for (int e = 0; e < 16; ++e) se[e] = 0.f;
#pragma unroll
        for (int i = 0; i < 5; ++i) {
            float E = __expf(li[i] - M);
            if (i == 4) E *= valid4;
            pe += E;
#pragma unroll
            for (int e = 0; e < 16; ++e) se[e] += E * (float)uhh[i][e >> 3][e & 7];
        }
#pragma unroll
        for (int m = 1; m < 64; m <<= 1) {
            pe += __shfl_xor(pe, m, 64);
#pragma unroll
            for (int e = 0; e < 16; ++e) se[e] += __shfl_xor(se[e], m, 64);
        }
        if (lane == 0) {
            red[w][16] = pe;
#pragma unroll
            for (int e = 0; e < 16; ++e) red[w][e] = se[e];
        }
        __syncthreads();
        float peT = red[0][16] + red[1][16] + red[2][16] + red[3][16];
        float rp = 1.f / peT;
        float nrm = 0.f;
#pragma unroll
        for (int e = 0; e < 16; ++e) {
            sv[e] = (red[0][e] + red[1][e] + red[2][e] + red[3][e]) * rp;
            nrm += sv[e] * sv[e];
        }
        float sc = nrm / ((nrm + 1.f) * (sqrtf(nrm) + EPS));
#pragma unroll
        for (int e = 0; e < 16; ++e) {
            sv[e] *= sc;
            vsum[e] += sv[e];
        }
        __syncthreads();
    }
    if (t == 0) {
#pragma unroll
        for (int e = 0; e < 16; ++e) v[(b * 10 + c) * 16 + e] = sv[e];
    }
}

// -------------- logits = softmax over c of ||v|| ---------------------------------------
__global__ __launch_bounds__(256) void logits_k(const float* __restrict__ v,
                                                float* __restrict__ out) {
    int b = threadIdx.x;
    float nr[10];
#pragma unroll
    for (int c = 0; c < 10; ++c) {
        float s2 = 0.f;
#pragma unroll
        for (int e = 0; e < 16; ++e) {
            float xv = v[(b * 10 + c) * 16 + e];
            s2 += xv * xv;
        }
        nr[c] = sqrtf(s2);
    }
    float mx = nr[0];
#pragma unroll
    for (int c = 1; c < 10; ++c) mx = fmaxf(mx, nr[c]);
    float ex[10], sm = 0.f;
#pragma unroll
    for (int c = 0; c < 10; ++c) {
        ex[c] = __expf(nr[c] - mx);
        sm += ex[c];
    }
#pragma unroll
    for (int c = 0; c < 10; ++c) out[b * 10 + c] = ex[c] / sm;
}

// -------------- fc1: picks the 16 columns selected by y ------------------------------
__global__ __launch_bounds__(256) void fc1_k(const float* __restrict__ v,
                                             const int* __restrict__ y,
                                             const float* __restrict__ w1,
                                             const float* __restrict__ b1,
                                             float* __restrict__ h1) {
    int b = blockIdx.x, t = threadIdx.x;
    __shared__ float vs[16];
    int cls = y[b];
    if (t < 16) vs[t] = v[(b * 10 + cls) * 16 + t];
    __syncthreads();
    for (int j = t; j < 512; j += 256) {
        float a = b1[j];
#pragma unroll
        for (int d = 0; d < 16; ++d) a += vs[d] * w1[(cls * 16 + d) * 512 + j];
        h1[b * 512 + j] = fmaxf(a, 0.f);
    }
}

// -------------- generic fc: C[256,N] = (relu?)(A[256,K] @ W[K,N] + bias) ---------------
__global__ __launch_bounds__(256) void fc_k(const float* __restrict__ A,
                                            const float* __restrict__ Wt,
                                            const float* __restrict__ bias,
                                            float* __restrict__ C,
                                            int K, int N, int relu) {
    __shared__ float al[8 * 1024];
    int t = threadIdx.x;
    int j = blockIdx.x * 256 + t;
    int r0 = blockIdx.y * 8;
    for (int idx = t; idx < 8 * K; idx += 256) {
        int r = idx / K, kk = idx - r * K;
        al[r * K + kk] = A[(r0 + r) * K + kk];
    }
    __syncthreads();
    if (j < N) {
        float bj = bias[j];
        float acc[8];
#pragma unroll
        for (int i = 0; i < 8; ++i) acc[i] = bj;
        for (int k = 0; k < K; ++k) {
            float w = Wt[(long)k * N + j];
#pragma unroll
            for (int i = 0; i < 8; ++i) acc[i] += al[i * K + k] * w;
        }
#pragma unroll
        for (int i = 0; i < 8; ++i) {
            float o = acc[i];
            if (relu) o = fmaxf(o, 0.f);
            C[(r0 + i) * N + j] = o;
        }
    }
}

extern "C" void kernel_launch(void* const* d_in, const int* in_sizes, int n_in,
                              void* d_out, int out_size, void* d_ws, size_t ws_size,
                              hipStream_t stream) {
    (void)in_sizes; (void)n_in; (void)out_size; (void)ws_size;
    const float* x       = (const float*)d_in[0];
    const int*   y       = (const int*)d_in[1];
    const float* conv1_w = (const float*)d_in[2];
    const float* conv1_b = (const float*)d_in[3];
    const float* prim_w  = (const float*)d_in[4];
    const float* prim_b  = (const float*)d_in[5];
    const float* route_W = (const float*)d_in[6];
    const float* dec_w1  = (const float*)d_in[7];
    const float* dec_b1  = (const float*)d_in[8];
    const float* dec_w2  = (const float*)d_in[9];
    const float* dec_b2  = (const float*)d_in[10];
    const float* dec_w3  = (const float*)d_in[11];
    const float* dec_b3  = (const float*)d_in[12];
    float* out = (float*)d_out;

    float* ws  = (float*)d_ws;
    float* Cp  = ws;                  // 4 * 2359296 f32 (ci-split partials)
    float* u   = Cp + 9437184;        // 2359296
    float* wt1 = u + 2359296;         // 20736
    float* v   = wt1 + 20736;         // 40960
    float* h1  = v + 40960;           // 131072
    float* h2  = h1 + 131072;         // 262144
    __half* hh = (__half*)(h2 + 262144);   // 26214400 halfs
    __half* w2 = hh + 26214400;            // 5308416 halfs
    // uh (fp16, 47185920 halfs = 94.4 MB) OVERLAYS hh/w2: both dead after primgemm_k,
    // and uhat_k (reader of u, writer of uh) runs after squashp_k (Cp dead too).
    __half* uhb = hh;

    hipLaunchKernelGGL(transpose_k, dim3(2, 4), dim3(256), 0, stream, conv1_w, wt1, 256, 81);
    hipLaunchKernelGGL(wprep_k, dim3(256, 2), dim3(256), 0, stream, prim_w, w2);
    hipLaunchKernelGGL(conv1_k, dim3(256, 4), dim3(256), 0, stream, x, wt1, conv1_b, hh);
    hipLaunchKernelGGL(primgemm_k, dim3(576), dim3(256), 0, stream, hh, w2, Cp);
    hipLaunchKernelGGL(squashp_k, dim3(256), dim3(256), 0, stream, Cp, prim_b, u);
    hipLaunchKernelGGL(uhat_k, dim3(360), dim3(256), 0, stream, u, route_W, uhb);
    hipLaunchKernelGGL(route2_k, dim3(2560), dim3(256), 0, stream, uhb, v);
    hipLaunchKernelGGL(logits_k, dim3(1), dim3(256), 0, stream, v, out);
    hipLaunchKernelGGL(fc1_k, dim3(256), dim3(256), 0, stream, v, y, dec_w1, dec_b1, h1);
    hipLaunchKernelGGL(fc_k, dim3(4, 32), dim3(256), 0, stream, h1, dec_w2, dec_b2, h2, 512, 1024, 1);
    hipLaunchKernelGGL(fc_k, dim3(4, 32), dim3(256), 0, stream, h2, dec_w3, dec_b3, out + 2560, 1024, 784, 0);
}